// Round 1
// baseline (1840.897 us; speedup 1.0000x reference)
//
#include <hip/hip_runtime.h>
#include <hip/hip_bf16.h>
#include <cstdint>
#include <cstddef>

#define TDIM 2048
#define NH 8

using f32x4 = __attribute__((ext_vector_type(4))) float;
using s16x8 = __attribute__((ext_vector_type(8))) short;

__device__ __forceinline__ float sigm(float x) { return 1.0f / (1.0f + __expf(-x)); }

#define GLDS(gp, lp)                                                          \
    __builtin_amdgcn_global_load_lds(                                         \
        (const __attribute__((address_space(1))) void*)(gp),                  \
        (__attribute__((address_space(3))) void*)(lp), 16, 0, 0)

// ---------------------------------------------------------------- pack kernels
__global__ __launch_bounds__(256) void pack_f32_bf16_kernel(
    const float* __restrict__ src, __hip_bfloat16* __restrict__ dst, int n4)
{
    int i = blockIdx.x * 256 + threadIdx.x;
    if (i >= n4) return;
    float4 v = *(const float4*)(src + (size_t)i * 4);
    size_t o = (size_t)i * 4;
    dst[o + 0] = __float2bfloat16(v.x);
    dst[o + 1] = __float2bfloat16(v.y);
    dst[o + 2] = __float2bfloat16(v.z);
    dst[o + 3] = __float2bfloat16(v.w);
}

__global__ __launch_bounds__(256) void pack_w_kernel(
    const float* __restrict__ Wq, const float* __restrict__ Wk,
    const float* __restrict__ Wv, const float* __restrict__ Wa,
    const float* __restrict__ Wb, const float* __restrict__ Wg,
    __hip_bfloat16* __restrict__ dst)
{
    int e = blockIdx.x * 256 + threadIdx.x;  // < 4224*1024
    int r = e >> 10, c = e & 1023;
    float vv;
    if      (r <  512) vv = Wq[(size_t)r * 1024 + c];
    else if (r < 1024) vv = Wk[(size_t)(r -  512) * 1024 + c];
    else if (r < 2048) vv = Wv[(size_t)(r - 1024) * 1024 + c];
    else if (r < 3072) vv = Wa[(size_t)(r - 2048) * 1024 + c];
    else if (r < 3080) vv = Wb[(size_t)(r - 3072) * 1024 + c];
    else if (r < 4104) vv = Wg[(size_t)(r - 3080) * 1024 + c];
    else               vv = 0.0f;
    dst[e] = __float2bfloat16(vv);
}

// ---------------------------------------------------------------- GEMM 1 (fused epilogue)
// C = A(8192x1024 bf16) * B^T(rows=4224 bf16), routed outputs per n-range.
__global__ __launch_bounds__(256) void gemm1_kernel(
    const __hip_bfloat16* __restrict__ A, const __hip_bfloat16* __restrict__ Bw,
    float* __restrict__ qraw, float* __restrict__ kraw, float* __restrict__ vraw,
    float* __restrict__ abuf, float* __restrict__ betab, float* __restrict__ gbuf,
    const float* __restrict__ ba, const float* __restrict__ bb)
{
    constexpr int Kd = 1024;
    __shared__ __attribute__((aligned(16))) __hip_bfloat16 At[128 * 32];
    __shared__ __attribute__((aligned(16))) __hip_bfloat16 Bt[128 * 32];
    const int tid = threadIdx.x;
    const int mBase = blockIdx.x * 128;
    const int nBase = blockIdx.y * 128;
    const int wave = tid >> 6, lane = tid & 63;
    const int wm = (wave >> 1) * 64, wn = (wave & 1) * 64;
    const int quad = lane >> 4, l16 = lane & 15;

    f32x4 acc[4][4];
    for (int i = 0; i < 4; i++)
        for (int j = 0; j < 4; j++)
            for (int r = 0; r < 4; r++) acc[i][j][r] = 0.0f;

    const int srow = tid >> 2;
    const int skk = (tid & 3) * 8;
    const __hip_bfloat16* Ag = A + (size_t)(mBase + srow) * Kd + skk;
    const __hip_bfloat16* Bg = Bw + (size_t)(nBase + srow) * Kd + skk;
    __hip_bfloat16* Al = &At[srow * 32 + skk];
    __hip_bfloat16* Bl = &Bt[srow * 32 + skk];

    for (int k0 = 0; k0 < Kd; k0 += 32) {
        GLDS(Ag + k0, Al);
        GLDS(Ag + k0 + (size_t)64 * Kd, Al + 64 * 32);
        GLDS(Bg + k0, Bl);
        GLDS(Bg + k0 + (size_t)64 * Kd, Bl + 64 * 32);
        __syncthreads();
        s16x8 af[4], bfr[4];
#pragma unroll
        for (int i = 0; i < 4; i++)
            af[i] = *(const s16x8*)&At[(wm + i * 16 + l16) * 32 + quad * 8];
#pragma unroll
        for (int j = 0; j < 4; j++)
            bfr[j] = *(const s16x8*)&Bt[(wn + j * 16 + l16) * 32 + quad * 8];
#pragma unroll
        for (int i = 0; i < 4; i++)
#pragma unroll
            for (int j = 0; j < 4; j++)
                acc[i][j] = __builtin_amdgcn_mfma_f32_16x16x32_bf16(af[i], bfr[j], acc[i][j], 0, 0, 0);
        __syncthreads();
    }

    for (int j = 0; j < 4; j++) {
        int n = nBase + wn + j * 16 + l16;
        for (int i = 0; i < 4; i++) {
            for (int r = 0; r < 4; r++) {
                int m = mBase + wm + i * 16 + quad * 4 + r;
                float val = acc[i][j][r];
                if (n < 512) qraw[(size_t)m * 512 + n] = val;
                else if (n < 1024) kraw[(size_t)m * 512 + n - 512] = val;
                else if (n < 2048) vraw[(size_t)m * 1024 + n - 1024] = val;
                else if (n < 3072) abuf[(size_t)m * 1024 + n - 2048] = sigm(val + ba[n - 2048]);
                else if (n < 3080) betab[(size_t)m * 8 + n - 3072] = sigm(val + bb[n - 3072]);
                else if (n < 4104) gbuf[(size_t)m * 1024 + n - 3080] = sigm(val);
            }
        }
    }
}

// ---------------------------------------------------------------- GEMM 2 (plain)
__global__ __launch_bounds__(256) void gemm2_kernel(
    const __hip_bfloat16* __restrict__ A, const __hip_bfloat16* __restrict__ Bw,
    float* __restrict__ out)
{
    constexpr int Kd = 1024;
    __shared__ __attribute__((aligned(16))) __hip_bfloat16 At[128 * 32];
    __shared__ __attribute__((aligned(16))) __hip_bfloat16 Bt[128 * 32];
    const int tid = threadIdx.x;
    const int mBase = blockIdx.x * 128;
    const int nBase = blockIdx.y * 128;
    const int wave = tid >> 6, lane = tid & 63;
    const int wm = (wave >> 1) * 64, wn = (wave & 1) * 64;
    const int quad = lane >> 4, l16 = lane & 15;

    f32x4 acc[4][4];
    for (int i = 0; i < 4; i++)
        for (int j = 0; j < 4; j++)
            for (int r = 0; r < 4; r++) acc[i][j][r] = 0.0f;

    const int srow = tid >> 2;
    const int skk = (tid & 3) * 8;
    const __hip_bfloat16* Ag = A + (size_t)(mBase + srow) * Kd + skk;
    const __hip_bfloat16* Bg = Bw + (size_t)(nBase + srow) * Kd + skk;
    __hip_bfloat16* Al = &At[srow * 32 + skk];
    __hip_bfloat16* Bl = &Bt[srow * 32 + skk];

    for (int k0 = 0; k0 < Kd; k0 += 32) {
        GLDS(Ag + k0, Al);
        GLDS(Ag + k0 + (size_t)64 * Kd, Al + 64 * 32);
        GLDS(Bg + k0, Bl);
        GLDS(Bg + k0 + (size_t)64 * Kd, Bl + 64 * 32);
        __syncthreads();
        s16x8 af[4], bfr[4];
#pragma unroll
        for (int i = 0; i < 4; i++)
            af[i] = *(const s16x8*)&At[(wm + i * 16 + l16) * 32 + quad * 8];
#pragma unroll
        for (int j = 0; j < 4; j++)
            bfr[j] = *(const s16x8*)&Bt[(wn + j * 16 + l16) * 32 + quad * 8];
#pragma unroll
        for (int i = 0; i < 4; i++)
#pragma unroll
            for (int j = 0; j < 4; j++)
                acc[i][j] = __builtin_amdgcn_mfma_f32_16x16x32_bf16(af[i], bfr[j], acc[i][j], 0, 0, 0);
        __syncthreads();
    }

    for (int j = 0; j < 4; j++) {
        int n = nBase + wn + j * 16 + l16;
        for (int i = 0; i < 4; i++) {
            for (int r = 0; r < 4; r++) {
                int m = mBase + wm + i * 16 + quad * 4 + r;
                out[(size_t)m * 1024 + n] = acc[i][j][r];
            }
        }
    }
}

// ---------------------------------------------------------------- depthwise causal conv (K=4) + SiLU
__global__ __launch_bounds__(256) void conv_silu_kernel(
    const float* __restrict__ src, const float* __restrict__ w4,
    const float* __restrict__ bias, float* __restrict__ dst,
    int C, int total, float scale)
{
    int e = blockIdx.x * 256 + threadIdx.x;
    if (e >= total) return;
    int c = e % C;
    int bt = e / C;
    int t = bt % TDIM;
    const float* wc = w4 + (size_t)c * 4;
    const float* s = src + (size_t)bt * C + c;
    float acc = bias[c];
    acc = fmaf(s[0], wc[3], acc);
    if (t >= 1) acc = fmaf(s[-C], wc[2], acc);
    if (t >= 2) acc = fmaf(s[-2 * C], wc[1], acc);
    if (t >= 3) acc = fmaf(s[-3 * C], wc[0], acc);
    dst[e] = acc * sigm(acc) * scale;
}

// ---------------------------------------------------------------- gated delta-rule scan
// 512 blocks x 64 threads. block -> (b, h, vg of 8 columns); lane = ks*8+vi.
// Each lane holds S[ks*8 .. ks*8+7][v] (8 floats). Cross-kslice dots via shfl_xor 8/16/32.
#define SCAN_LOAD(K0, K1, Q0, Q1, VV, AA, BB, TT) do {                        \
    size_t ko = kqBase + (size_t)(TT) * 512;                                  \
    K0 = *(const float4*)(kc + ko); K1 = *(const float4*)(kc + ko + 4);       \
    Q0 = *(const float4*)(qc + ko); Q1 = *(const float4*)(qc + ko + 4);       \
    size_t vo = vaBase + (size_t)(TT) * 1024;                                 \
    VV = vc[vo]; AA = ab[vo]; BB = betab[beBase + (size_t)(TT) * 8];          \
} while (0)

#define SCAN_STEP(K0, K1, Q0, Q1, VV, AA, BB, TT) do {                        \
    float r0 = K0.x * S0, r1 = K0.y * S1;                                     \
    r0 = fmaf(K0.z, S2, r0); r1 = fmaf(K0.w, S3, r1);                         \
    r0 = fmaf(K1.x, S4, r0); r1 = fmaf(K1.y, S5, r1);                         \
    r0 = fmaf(K1.z, S6, r0); r1 = fmaf(K1.w, S7, r1);                         \
    float rr = r0 + r1;                                                       \
    rr += __shfl_xor(rr, 8); rr += __shfl_xor(rr, 16); rr += __shfl_xor(rr, 32); \
    float cc = BB * (rr - VV);                                                \
    float o0, o1;                                                             \
    S0 = fmaf(-cc, K0.x, AA * S0); o0 = Q0.x * S0;                            \
    S1 = fmaf(-cc, K0.y, AA * S1); o1 = Q0.y * S1;                            \
    S2 = fmaf(-cc, K0.z, AA * S2); o0 = fmaf(Q0.z, S2, o0);                   \
    S3 = fmaf(-cc, K0.w, AA * S3); o1 = fmaf(Q0.w, S3, o1);                   \
    S4 = fmaf(-cc, K1.x, AA * S4); o0 = fmaf(Q1.x, S4, o0);                   \
    S5 = fmaf(-cc, K1.y, AA * S5); o1 = fmaf(Q1.y, S5, o1);                   \
    S6 = fmaf(-cc, K1.z, AA * S6); o0 = fmaf(Q1.z, S6, o0);                   \
    S7 = fmaf(-cc, K1.w, AA * S7); o1 = fmaf(Q1.w, S7, o1);                   \
    float oo = o0 + o1;                                                       \
    oo += __shfl_xor(oo, 8); oo += __shfl_xor(oo, 16); oo += __shfl_xor(oo, 32); \
    if (ks == 0) ob[vaBase + (size_t)(TT) * 1024] = oo;                       \
} while (0)

__global__ __launch_bounds__(64) void scan_kernel(
    const float* __restrict__ qc, const float* __restrict__ kc,
    const float* __restrict__ vc, const float* __restrict__ ab,
    const float* __restrict__ betab, float* __restrict__ ob)
{
    const int bid = blockIdx.x;
    const int vg = bid & 15, h = (bid >> 4) & 7, b = bid >> 7;
    const int lane = threadIdx.x;
    const int vi = lane & 7, ks = lane >> 3;
    const int v = vg * 8 + vi;
    float S0 = 0, S1 = 0, S2 = 0, S3 = 0, S4 = 0, S5 = 0, S6 = 0, S7 = 0;
    const size_t kqBase = ((size_t)b * TDIM * NH + h) * 64 + (size_t)ks * 8;  // stride 512/t
    const size_t vaBase = ((size_t)b * TDIM * NH + h) * 128 + v;              // stride 1024/t
    const size_t beBase = (size_t)b * TDIM * 8 + h;                           // stride 8/t

    float4 kA0, kA1, qA0, qA1; float vA, aA, btA;
    float4 kB0, kB1, qB0, qB1; float vB, aB, btB;
    SCAN_LOAD(kA0, kA1, qA0, qA1, vA, aA, btA, 0);
    for (int t = 0; t < TDIM; t += 2) {
        SCAN_LOAD(kB0, kB1, qB0, qB1, vB, aB, btB, t + 1);
        SCAN_STEP(kA0, kA1, qA0, qA1, vA, aA, btA, t);
        int t2 = (t + 2 < TDIM) ? (t + 2) : 0;
        SCAN_LOAD(kA0, kA1, qA0, qA1, vA, aA, btA, t2);
        SCAN_STEP(kB0, kB1, qB0, qB1, vB, aB, btB, t + 1);
    }
}

// ---------------------------------------------------------------- LayerNorm(DV=128) + gate -> bf16
__global__ __launch_bounds__(256) void ln_gate_kernel(
    const float* __restrict__ ob, const float* __restrict__ g,
    const float* __restrict__ lnw, const float* __restrict__ lnb,
    __hip_bfloat16* __restrict__ opr)
{
    int row = blockIdx.x * 4 + (threadIdx.x >> 6);
    int lane = threadIdx.x & 63;
    size_t base = (size_t)row * 128 + lane * 2;
    float2 xv = *(const float2*)(ob + base);
    float s = xv.x + xv.y;
#pragma unroll
    for (int m = 1; m <= 32; m <<= 1) s += __shfl_xor(s, m);
    float mean = s * (1.0f / 128.0f);
    float d0 = xv.x - mean, d1 = xv.y - mean;
    float vs = d0 * d0 + d1 * d1;
#pragma unroll
    for (int m = 1; m <= 32; m <<= 1) vs += __shfl_xor(vs, m);
    float rstd = rsqrtf(vs * (1.0f / 128.0f) + 1e-5f);
    float2 gv = *(const float2*)(g + base);
    float w0 = lnw[lane * 2], w1 = lnw[lane * 2 + 1];
    float b0 = lnb[lane * 2], b1 = lnb[lane * 2 + 1];
    opr[base] = __float2bfloat16((d0 * rstd * w0 + b0) * gv.x);
    opr[base + 1] = __float2bfloat16((d1 * rstd * w1 + b1) * gv.y);
}

// ---------------------------------------------------------------- launch
extern "C" void kernel_launch(void* const* d_in, const int* in_sizes, int n_in,
                              void* d_out, int out_size, void* d_ws, size_t ws_size,
                              hipStream_t stream)
{
    const float* x    = (const float*)d_in[0];
    const float* Wq   = (const float*)d_in[1];
    const float* Wk   = (const float*)d_in[2];
    const float* Wv   = (const float*)d_in[3];
    const float* Wa   = (const float*)d_in[4];
    const float* ba   = (const float*)d_in[5];
    const float* Wb   = (const float*)d_in[6];
    const float* bb   = (const float*)d_in[7];
    const float* Wg   = (const float*)d_in[8];
    const float* Wo   = (const float*)d_in[9];
    const float* qc_w = (const float*)d_in[10];
    const float* qc_b = (const float*)d_in[11];
    const float* kc_w = (const float*)d_in[12];
    const float* kc_b = (const float*)d_in[13];
    const float* vc_w = (const float*)d_in[14];
    const float* vc_b = (const float*)d_in[15];
    const float* ln_w = (const float*)d_in[16];
    const float* ln_b = (const float*)d_in[17];
    float* out = (float*)d_out;

    char* W = (char*)d_ws;
    // arena (byte offsets); high-water ~212 MB
    __hip_bfloat16* xbf  = (__hip_bfloat16*)(W + 0);            // 16777216
    __hip_bfloat16* wcat = (__hip_bfloat16*)(W + 16777216);     // 8650752
    __hip_bfloat16* wobf = (__hip_bfloat16*)(W + 25427968);     // 2097152
    float* qraw  = (float*)(W + 27525120);                      // 16777216
    float* kraw  = (float*)(W + 44302336);                      // 16777216
    float* vraw  = (float*)(W + 61079552);                      // 33554432
    float* abuf  = (float*)(W + 94633984);                      // 33554432
    float* betab = (float*)(W + 128188416);                     // 262144
    float* gbuf  = (float*)(W + 128450560);                     // 33554432
    float* kcb   = (float*)(W + 162004992);                     // 16777216
    float* vcb   = (float*)(W + 178782208);                     // 33554432
    float* qcb   = (float*)xbf;                 // reuse: xbf dead after gemm1
    float* obuf  = (float*)qraw;                // reuse: qraw+kraw dead after convs (33.5MB)
    __hip_bfloat16* opr = (__hip_bfloat16*)vraw;// reuse: vraw dead after conv-v

    // 1) packs
    pack_f32_bf16_kernel<<<8192, 256, 0, stream>>>(x, xbf, 2097152);
    pack_w_kernel<<<16896, 256, 0, stream>>>(Wq, Wk, Wv, Wa, Wb, Wg, wcat);
    pack_f32_bf16_kernel<<<1024, 256, 0, stream>>>(Wo, wobf, 262144);
    // 2) fused projection GEMM (M=8192, N=4224 padded, K=1024)
    gemm1_kernel<<<dim3(64, 33), 256, 0, stream>>>(xbf, wcat, qraw, kraw, vraw,
                                                   abuf, betab, gbuf, ba, bb);
    // 3) convs + SiLU (k also scaled by DK^-0.5)
    conv_silu_kernel<<<16384, 256, 0, stream>>>(qraw, qc_w, qc_b, qcb, 512, 4194304, 1.0f);
    conv_silu_kernel<<<16384, 256, 0, stream>>>(kraw, kc_w, kc_b, kcb, 512, 4194304, 0.125f);
    conv_silu_kernel<<<32768, 256, 0, stream>>>(vraw, vc_w, vc_b, vcb, 1024, 8388608, 1.0f);
    // 4) gated delta-rule scan
    scan_kernel<<<512, 64, 0, stream>>>(qcb, kcb, vcb, abuf, betab, obuf);
    // 5) LayerNorm + gate -> bf16
    ln_gate_kernel<<<16384, 256, 0, stream>>>(obuf, gbuf, ln_w, ln_b, opr);
    // 6) output GEMM (M=8192, N=1024, K=1024)
    gemm2_kernel<<<dim3(64, 8), 256, 0, stream>>>(opr, wobf, out);
}